// Round 1
// baseline (5355.130 us; speedup 1.0000x reference)
//
#include <hip/hip_runtime.h>
#include <math.h>

#define N_NODES 50000
#define M_ENS   20
#define C_IN    32
#define H       128
#define E_EDGES 800000
#define L_LAYERS 3
#define BN_EPS  1e-5f

// ---------------------------------------------------------------------------
// K1: fused per-node ensemble embedding:
//   phi = relu(ens @ w1 + b1) @ w2 + b2 ; agg = sum_m phi
//   emb = relu(agg @ rw1 + rb1) @ rw2 + rb2
//   h   = concat(x, emb) @ dr_w + dr_b
// One node per 256-thread block.
// ---------------------------------------------------------------------------
__global__ __launch_bounds__(256) void k_embed(
    const float* __restrict__ ensemble, const float* __restrict__ x,
    const float* __restrict__ phi_w1, const float* __restrict__ phi_b1,
    const float* __restrict__ phi_w2, const float* __restrict__ phi_b2,
    const float* __restrict__ rho_w1, const float* __restrict__ rho_b1,
    const float* __restrict__ rho_w2, const float* __restrict__ rho_b2,
    const float* __restrict__ dr_w,   const float* __restrict__ dr_b,
    float* __restrict__ h_out)
{
    const int n = blockIdx.x;
    const int t = threadIdx.x;

    __shared__ float s_ens[M_ENS * C_IN];   // 640
    __shared__ float s_hid[M_ENS * H];      // 2560
    __shared__ float s_red[256];
    __shared__ float s_agg[H];
    __shared__ float s_t1[H];
    __shared__ float s_emb[H];
    __shared__ float s_x[C_IN];

    // stage inputs
    for (int i = t; i < M_ENS * C_IN; i += 256)
        s_ens[i] = ensemble[(size_t)n * (M_ENS * C_IN) + i];
    if (t < C_IN) s_x[t] = x[(size_t)n * C_IN + t];
    __syncthreads();

    // phi layer 1: hid[m][j] = relu(b1[j] + sum_k ens[m][k] * w1[k][j])
    for (int o = t; o < M_ENS * H; o += 256) {
        const int m = o >> 7;
        const int j = o & 127;
        float acc = phi_b1[j];
        #pragma unroll
        for (int k = 0; k < C_IN; ++k)
            acc = fmaf(s_ens[m * C_IN + k], phi_w1[k * H + j], acc);
        s_hid[o] = fmaxf(acc, 0.f);
    }
    __syncthreads();

    // phi layer 2 summed over m:  agg[j] = sum_m (hid[m] . w2[:,j]) + M*b2[j]
    {
        const int j = t & 127;
        const int g = t >> 7;          // two m-groups of 10
        const int m0 = g * 10;
        float acc = 0.f;
        for (int k = 0; k < H; ++k) {
            const float wv = phi_w2[k * H + j];
            #pragma unroll
            for (int mm = 0; mm < 10; ++mm)
                acc = fmaf(s_hid[(m0 + mm) * H + k], wv, acc);
        }
        s_red[t] = acc;
    }
    __syncthreads();
    if (t < H)
        s_agg[t] = s_red[t] + s_red[t + 128] + (float)M_ENS * phi_b2[t];
    __syncthreads();

    // rho layer 1
    if (t < H) {
        float acc = rho_b1[t];
        for (int k = 0; k < H; ++k)
            acc = fmaf(s_agg[k], rho_w1[k * H + t], acc);
        s_t1[t] = fmaxf(acc, 0.f);
    }
    __syncthreads();
    // rho layer 2
    if (t < H) {
        float acc = rho_b2[t];
        for (int k = 0; k < H; ++k)
            acc = fmaf(s_t1[k], rho_w2[k * H + t], acc);
        s_emb[t] = acc;
    }
    __syncthreads();
    // dr: h = concat(x, emb) @ dr_w + dr_b
    if (t < H) {
        float acc = dr_b[t];
        #pragma unroll
        for (int k = 0; k < C_IN; ++k)
            acc = fmaf(s_x[k], dr_w[k * H + t], acc);
        for (int k = 0; k < H; ++k)
            acc = fmaf(s_emb[k], dr_w[(C_IN + k) * H + t], acc);
        h_out[(size_t)n * H + t] = acc;
    }
}

// ---------------------------------------------------------------------------
// K2: edge messages + scatter-add.
//   msg = relu(h[src] + ea*ew + eb); agg[dst] += msg
// 32 threads per edge, 4 channels each (float4), atomicAdd into agg.
// ---------------------------------------------------------------------------
__global__ __launch_bounds__(256) void k_edge(
    const int* __restrict__ ei, const float* __restrict__ ea,
    const float* __restrict__ h, const float* __restrict__ ew,
    const float* __restrict__ eb, float* __restrict__ agg)
{
    const int gid = blockIdx.x * 256 + threadIdx.x;
    const int e = gid >> 5;
    if (e >= E_EDGES) return;
    const int c = (gid & 31) * 4;
    const int src = ei[e];
    const int dst = ei[E_EDGES + e];
    const float a = ea[e];

    const float4 hv = *(const float4*)&h[(size_t)src * H + c];
    const float4 wv = *(const float4*)&ew[c];
    const float4 bv = *(const float4*)&eb[c];

    const float m0 = fmaxf(fmaf(a, wv.x, hv.x) + bv.x, 0.f);
    const float m1 = fmaxf(fmaf(a, wv.y, hv.y) + bv.y, 0.f);
    const float m2 = fmaxf(fmaf(a, wv.z, hv.z) + bv.z, 0.f);
    const float m3 = fmaxf(fmaf(a, wv.w, hv.w) + bv.w, 0.f);

    float* base = &agg[(size_t)dst * H + c];
    atomicAdd(base + 0, m0);
    atomicAdd(base + 1, m1);
    atomicAdd(base + 2, m2);
    atomicAdd(base + 3, m3);
}

// ---------------------------------------------------------------------------
// K3: GINE node update (per layer):
//   z = (1+eps)*h + agg; z = BN(z@w1+b1); z = relu(z); c = z@w2+b2
//   h = relu(c) (layer 0) or h + relu(c)
// 8 nodes per 256-thread block; thread owns (j, 4 nodes) for register reuse.
// ---------------------------------------------------------------------------
#define NPB 8
__global__ __launch_bounds__(256) void k_gine(
    const float* __restrict__ agg, float* __restrict__ h,
    const float* __restrict__ eps_p,
    const float* __restrict__ w1, const float* __restrict__ b1,
    const float* __restrict__ bn_g, const float* __restrict__ bn_b,
    const float* __restrict__ bn_m, const float* __restrict__ bn_v,
    const float* __restrict__ w2, const float* __restrict__ b2,
    const int first_layer)
{
    const int n0 = blockIdx.x * NPB;
    const int t = threadIdx.x;
    const int j = t & 127;
    const int grp = t >> 7;            // 0 or 1
    const int q0 = grp * 4;            // node sub-range within block

    __shared__ float s_z[NPB][H];
    __shared__ float s_t[NPB][H];
    __shared__ float s_h[NPB][H];

    const float ep1 = 1.f + eps_p[0];

    for (int i = t; i < NPB * H; i += 256) {
        const int q = i >> 7, c = i & 127;
        const int n = n0 + q;
        const float hv = h[(size_t)n * H + c];
        const float av = agg[(size_t)n * H + c];
        s_h[q][c] = hv;
        s_z[q][c] = fmaf(ep1, hv, av);
    }
    __syncthreads();

    // z @ w1 + b1 -> BN -> relu
    {
        float acc[4] = {0.f, 0.f, 0.f, 0.f};
        for (int k = 0; k < H; ++k) {
            const float wv = w1[k * H + j];
            #pragma unroll
            for (int q = 0; q < 4; ++q)
                acc[q] = fmaf(s_z[q0 + q][k], wv, acc[q]);
        }
        const float bb = b1[j];
        const float scale = bn_g[j] * rsqrtf(bn_v[j] + BN_EPS);
        const float shift = bn_b[j] - bn_m[j] * scale;
        #pragma unroll
        for (int q = 0; q < 4; ++q)
            s_t[q0 + q][j] = fmaxf(fmaf(acc[q] + bb, scale, shift), 0.f);
    }
    __syncthreads();

    // t @ w2 + b2 -> relu -> residual -> writeback
    {
        float acc[4] = {0.f, 0.f, 0.f, 0.f};
        for (int k = 0; k < H; ++k) {
            const float wv = w2[k * H + j];
            #pragma unroll
            for (int q = 0; q < 4; ++q)
                acc[q] = fmaf(s_t[q0 + q][k], wv, acc[q]);
        }
        const float bb = b2[j];
        #pragma unroll
        for (int q = 0; q < 4; ++q) {
            const int n = n0 + q0 + q;
            const float r = fmaxf(acc[q] + bb, 0.f);
            h[(size_t)n * H + j] = first_layer ? r : (s_h[q0 + q][j] + r);
        }
    }
}

// ---------------------------------------------------------------------------
// K4: output head: out = h @ aggr_w + aggr_b; mu = out[:,0]; sigma = softplus(out[:,1])
// 2 nodes per 256-thread block, LDS tree reduce over 128 channels.
// ---------------------------------------------------------------------------
__global__ __launch_bounds__(256) void k_out(
    const float* __restrict__ h, const float* __restrict__ aw,
    const float* __restrict__ ab, float* __restrict__ out)
{
    const int n = blockIdx.x * 2 + (threadIdx.x >> 7);
    const int j = threadIdx.x & 127;
    const int base = (threadIdx.x >> 7) << 7;

    __shared__ float r0[256];
    __shared__ float r1[256];

    const float hv = h[(size_t)n * H + j];
    r0[threadIdx.x] = hv * aw[j * 2 + 0];
    r1[threadIdx.x] = hv * aw[j * 2 + 1];
    __syncthreads();

    for (int s = 64; s > 0; s >>= 1) {
        if (j < s) {
            r0[base + j] += r0[base + j + s];
            r1[base + j] += r1[base + j + s];
        }
        __syncthreads();
    }
    if (j == 0) {
        const float mu = r0[base] + ab[0];
        const float o1 = r1[base] + ab[1];
        // stable softplus
        const float sp = (o1 > 0.f) ? (o1 + log1pf(expf(-o1)))
                                    : log1pf(expf(o1));
        out[(size_t)n * 2 + 0] = mu;
        out[(size_t)n * 2 + 1] = sp;
    }
}

// ---------------------------------------------------------------------------
extern "C" void kernel_launch(void* const* d_in, const int* in_sizes, int n_in,
                              void* d_out, int out_size, void* d_ws, size_t ws_size,
                              hipStream_t stream)
{
    const float* ensemble = (const float*)d_in[0];
    const float* x        = (const float*)d_in[1];
    const int*   ei       = (const int*)d_in[2];
    const float* ea       = (const float*)d_in[3];
    const float* phi_w1   = (const float*)d_in[4];
    const float* phi_b1   = (const float*)d_in[5];
    const float* phi_w2   = (const float*)d_in[6];
    const float* phi_b2   = (const float*)d_in[7];
    const float* rho_w1   = (const float*)d_in[8];
    const float* rho_b1   = (const float*)d_in[9];
    const float* rho_w2   = (const float*)d_in[10];
    const float* rho_b2   = (const float*)d_in[11];
    const float* dr_w     = (const float*)d_in[12];
    const float* dr_b     = (const float*)d_in[13];
    const float* conv_eps = (const float*)d_in[14];
    const float* edge_w   = (const float*)d_in[15];
    const float* edge_b   = (const float*)d_in[16];
    const float* mlp_w1   = (const float*)d_in[17];
    const float* mlp_b1   = (const float*)d_in[18];
    const float* bn_g     = (const float*)d_in[19];
    const float* bn_b     = (const float*)d_in[20];
    const float* bn_m     = (const float*)d_in[21];
    const float* bn_v     = (const float*)d_in[22];
    const float* mlp_w2   = (const float*)d_in[23];
    const float* mlp_b2   = (const float*)d_in[24];
    const float* aggr_w   = (const float*)d_in[25];
    const float* aggr_b   = (const float*)d_in[26];

    float* out = (float*)d_out;

    // workspace: h (N*H) then agg (N*H)
    float* h_buf   = (float*)d_ws;
    float* agg_buf = h_buf + (size_t)N_NODES * H;

    // K1: node embeddings -> h
    k_embed<<<N_NODES, 256, 0, stream>>>(
        ensemble, x, phi_w1, phi_b1, phi_w2, phi_b2,
        rho_w1, rho_b1, rho_w2, rho_b2, dr_w, dr_b, h_buf);

    // GINE layers
    const int edge_blocks = (E_EDGES * 32) / 256;   // 100000 exact
    const int gine_blocks = N_NODES / NPB;          // 6250 exact
    for (int i = 0; i < L_LAYERS; ++i) {
        hipMemsetAsync(agg_buf, 0, (size_t)N_NODES * H * sizeof(float), stream);
        k_edge<<<edge_blocks, 256, 0, stream>>>(
            ei, ea, h_buf, edge_w + (size_t)i * H, edge_b + (size_t)i * H, agg_buf);
        k_gine<<<gine_blocks, 256, 0, stream>>>(
            agg_buf, h_buf, conv_eps + i,
            mlp_w1 + (size_t)i * H * H, mlp_b1 + (size_t)i * H,
            bn_g + (size_t)i * H, bn_b + (size_t)i * H,
            bn_m + (size_t)i * H, bn_v + (size_t)i * H,
            mlp_w2 + (size_t)i * H * H, mlp_b2 + (size_t)i * H,
            (i == 0) ? 1 : 0);
    }

    // K4: output head
    k_out<<<N_NODES / 2, 256, 0, stream>>>(h_buf, aggr_w, aggr_b, out);
}

// Round 2
// 1735.276 us; speedup vs baseline: 3.0860x; 3.0860x over previous
//
#include <hip/hip_runtime.h>
#include <math.h>

#define N_NODES 50000
#define M_ENS   20
#define C_IN    32
#define H       128
#define E_EDGES 800000
#define L_LAYERS 3
#define BN_EPS  1e-5f

// ---------------------------------------------------------------------------
// K1: fused per-node ensemble embedding (unchanged from R1):
//   phi = relu(ens @ w1 + b1) @ w2 + b2 ; agg = sum_m phi
//   emb = relu(agg @ rw1 + rb1) @ rw2 + rb2
//   h   = concat(x, emb) @ dr_w + dr_b
// One node per 256-thread block.
// ---------------------------------------------------------------------------
__global__ __launch_bounds__(256) void k_embed(
    const float* __restrict__ ensemble, const float* __restrict__ x,
    const float* __restrict__ phi_w1, const float* __restrict__ phi_b1,
    const float* __restrict__ phi_w2, const float* __restrict__ phi_b2,
    const float* __restrict__ rho_w1, const float* __restrict__ rho_b1,
    const float* __restrict__ rho_w2, const float* __restrict__ rho_b2,
    const float* __restrict__ dr_w,   const float* __restrict__ dr_b,
    float* __restrict__ h_out)
{
    const int n = blockIdx.x;
    const int t = threadIdx.x;

    __shared__ float s_ens[M_ENS * C_IN];   // 640
    __shared__ float s_hid[M_ENS * H];      // 2560
    __shared__ float s_red[256];
    __shared__ float s_agg[H];
    __shared__ float s_t1[H];
    __shared__ float s_emb[H];
    __shared__ float s_x[C_IN];

    for (int i = t; i < M_ENS * C_IN; i += 256)
        s_ens[i] = ensemble[(size_t)n * (M_ENS * C_IN) + i];
    if (t < C_IN) s_x[t] = x[(size_t)n * C_IN + t];
    __syncthreads();

    // phi layer 1
    for (int o = t; o < M_ENS * H; o += 256) {
        const int m = o >> 7;
        const int j = o & 127;
        float acc = phi_b1[j];
        #pragma unroll
        for (int k = 0; k < C_IN; ++k)
            acc = fmaf(s_ens[m * C_IN + k], phi_w1[k * H + j], acc);
        s_hid[o] = fmaxf(acc, 0.f);
    }
    __syncthreads();

    // phi layer 2 summed over m
    {
        const int j = t & 127;
        const int g = t >> 7;
        const int m0 = g * 10;
        float acc = 0.f;
        for (int k = 0; k < H; ++k) {
            const float wv = phi_w2[k * H + j];
            #pragma unroll
            for (int mm = 0; mm < 10; ++mm)
                acc = fmaf(s_hid[(m0 + mm) * H + k], wv, acc);
        }
        s_red[t] = acc;
    }
    __syncthreads();
    if (t < H)
        s_agg[t] = s_red[t] + s_red[t + 128] + (float)M_ENS * phi_b2[t];
    __syncthreads();

    if (t < H) {
        float acc = rho_b1[t];
        for (int k = 0; k < H; ++k)
            acc = fmaf(s_agg[k], rho_w1[k * H + t], acc);
        s_t1[t] = fmaxf(acc, 0.f);
    }
    __syncthreads();
    if (t < H) {
        float acc = rho_b2[t];
        for (int k = 0; k < H; ++k)
            acc = fmaf(s_t1[k], rho_w2[k * H + t], acc);
        s_emb[t] = acc;
    }
    __syncthreads();
    if (t < H) {
        float acc = dr_b[t];
        #pragma unroll
        for (int k = 0; k < C_IN; ++k)
            acc = fmaf(s_x[k], dr_w[k * H + t], acc);
        for (int k = 0; k < H; ++k)
            acc = fmaf(s_emb[k], dr_w[(C_IN + k) * H + t], acc);
        h_out[(size_t)n * H + t] = acc;
    }
}

// ---------------------------------------------------------------------------
// CSR build (edge_index is layer-invariant; built once per launch).
// ---------------------------------------------------------------------------
__global__ __launch_bounds__(256) void k_count(
    const int* __restrict__ ei, int* __restrict__ deg)
{
    const int e = blockIdx.x * 256 + threadIdx.x;
    if (e >= E_EDGES) return;
    atomicAdd(&deg[ei[E_EDGES + e]], 1);
}

// Single-block exclusive scan over N_NODES degrees (in place in `off`),
// also initializes `cursor` with the same offsets. off[N_NODES] = E.
__global__ __launch_bounds__(1024) void k_scan(
    int* __restrict__ off, int* __restrict__ cursor)
{
    const int t = threadIdx.x;
    const int CHUNK = (N_NODES + 1023) / 1024;   // 49
    const int lo = t * CHUNK;
    const int hi = min(lo + CHUNK, N_NODES);

    int mysum = 0;
    for (int i = lo; i < hi; ++i) mysum += off[i];

    __shared__ int s[1024];
    s[t] = mysum;
    __syncthreads();
    for (int d = 1; d < 1024; d <<= 1) {
        int v = (t >= d) ? s[t - d] : 0;
        __syncthreads();
        s[t] += v;
        __syncthreads();
    }
    int running = s[t] - mysum;   // exclusive prefix for this chunk

    for (int i = lo; i < hi; ++i) {
        const int d = off[i];     // read degree before overwrite
        off[i] = running;
        cursor[i] = running;
        running += d;
    }
    if (t == 0) off[N_NODES] = E_EDGES;
}

__global__ __launch_bounds__(256) void k_fill(
    const int* __restrict__ ei, const float* __restrict__ ea,
    int* __restrict__ cursor,
    int* __restrict__ csr_src, float* __restrict__ csr_a)
{
    const int e = blockIdx.x * 256 + threadIdx.x;
    if (e >= E_EDGES) return;
    const int dst = ei[E_EDGES + e];
    const int pos = atomicAdd(&cursor[dst], 1);
    csr_src[pos] = ei[e];
    csr_a[pos]   = ea[e];
}

// ---------------------------------------------------------------------------
// K2': gather-based aggregation (replaces atomic scatter).
//   agg[n] = sum_{e: dst(e)==n} relu(h[src(e)] + a_e*ew + eb)
// One wave per node; lane owns 2 channels (float2, 512B/wave/edge coalesced).
// h (25.6 MB) fits in L3 -> gather traffic is L3-served.
// ---------------------------------------------------------------------------
__global__ __launch_bounds__(256) void k_agg(
    const int* __restrict__ off, const int* __restrict__ csr_src,
    const float* __restrict__ csr_a,
    const float* __restrict__ h, const float* __restrict__ ew,
    const float* __restrict__ eb, float* __restrict__ agg)
{
    const int wave = threadIdx.x >> 6;
    const int lane = threadIdx.x & 63;
    const int n = blockIdx.x * 4 + wave;          // grid = 12500 exact
    const int c = lane * 2;

    const float2 wv = *(const float2*)&ew[c];
    const float2 bv = *(const float2*)&eb[c];

    float a0 = 0.f, a1 = 0.f;
    const int s = off[n], e = off[n + 1];
    for (int i = s; i < e; ++i) {
        const int   src = csr_src[i];
        const float a   = csr_a[i];
        const float2 hv = *(const float2*)&h[(size_t)src * H + c];
        a0 += fmaxf(fmaf(a, wv.x, hv.x) + bv.x, 0.f);
        a1 += fmaxf(fmaf(a, wv.y, hv.y) + bv.y, 0.f);
    }
    float2 r; r.x = a0; r.y = a1;
    *(float2*)&agg[(size_t)n * H + c] = r;
}

// ---------------------------------------------------------------------------
// K3: GINE node update (unchanged).
// ---------------------------------------------------------------------------
#define NPB 8
__global__ __launch_bounds__(256) void k_gine(
    const float* __restrict__ agg, float* __restrict__ h,
    const float* __restrict__ eps_p,
    const float* __restrict__ w1, const float* __restrict__ b1,
    const float* __restrict__ bn_g, const float* __restrict__ bn_b,
    const float* __restrict__ bn_m, const float* __restrict__ bn_v,
    const float* __restrict__ w2, const float* __restrict__ b2,
    const int first_layer)
{
    const int n0 = blockIdx.x * NPB;
    const int t = threadIdx.x;
    const int j = t & 127;
    const int grp = t >> 7;
    const int q0 = grp * 4;

    __shared__ float s_z[NPB][H];
    __shared__ float s_t[NPB][H];
    __shared__ float s_h[NPB][H];

    const float ep1 = 1.f + eps_p[0];

    for (int i = t; i < NPB * H; i += 256) {
        const int q = i >> 7, c = i & 127;
        const int n = n0 + q;
        const float hv = h[(size_t)n * H + c];
        const float av = agg[(size_t)n * H + c];
        s_h[q][c] = hv;
        s_z[q][c] = fmaf(ep1, hv, av);
    }
    __syncthreads();

    {
        float acc[4] = {0.f, 0.f, 0.f, 0.f};
        for (int k = 0; k < H; ++k) {
            const float wv = w1[k * H + j];
            #pragma unroll
            for (int q = 0; q < 4; ++q)
                acc[q] = fmaf(s_z[q0 + q][k], wv, acc[q]);
        }
        const float bb = b1[j];
        const float scale = bn_g[j] * rsqrtf(bn_v[j] + BN_EPS);
        const float shift = bn_b[j] - bn_m[j] * scale;
        #pragma unroll
        for (int q = 0; q < 4; ++q)
            s_t[q0 + q][j] = fmaxf(fmaf(acc[q] + bb, scale, shift), 0.f);
    }
    __syncthreads();

    {
        float acc[4] = {0.f, 0.f, 0.f, 0.f};
        for (int k = 0; k < H; ++k) {
            const float wv = w2[k * H + j];
            #pragma unroll
            for (int q = 0; q < 4; ++q)
                acc[q] = fmaf(s_t[q0 + q][k], wv, acc[q]);
        }
        const float bb = b2[j];
        #pragma unroll
        for (int q = 0; q < 4; ++q) {
            const int n = n0 + q0 + q;
            const float r = fmaxf(acc[q] + bb, 0.f);
            h[(size_t)n * H + j] = first_layer ? r : (s_h[q0 + q][j] + r);
        }
    }
}

// ---------------------------------------------------------------------------
// K4: output head (unchanged).
// ---------------------------------------------------------------------------
__global__ __launch_bounds__(256) void k_out(
    const float* __restrict__ h, const float* __restrict__ aw,
    const float* __restrict__ ab, float* __restrict__ out)
{
    const int n = blockIdx.x * 2 + (threadIdx.x >> 7);
    const int j = threadIdx.x & 127;
    const int base = (threadIdx.x >> 7) << 7;

    __shared__ float r0[256];
    __shared__ float r1[256];

    const float hv = h[(size_t)n * H + j];
    r0[threadIdx.x] = hv * aw[j * 2 + 0];
    r1[threadIdx.x] = hv * aw[j * 2 + 1];
    __syncthreads();

    for (int s = 64; s > 0; s >>= 1) {
        if (j < s) {
            r0[base + j] += r0[base + j + s];
            r1[base + j] += r1[base + j + s];
        }
        __syncthreads();
    }
    if (j == 0) {
        const float mu = r0[base] + ab[0];
        const float o1 = r1[base] + ab[1];
        const float sp = (o1 > 0.f) ? (o1 + log1pf(expf(-o1)))
                                    : log1pf(expf(o1));
        out[(size_t)n * 2 + 0] = mu;
        out[(size_t)n * 2 + 1] = sp;
    }
}

// ---------------------------------------------------------------------------
extern "C" void kernel_launch(void* const* d_in, const int* in_sizes, int n_in,
                              void* d_out, int out_size, void* d_ws, size_t ws_size,
                              hipStream_t stream)
{
    const float* ensemble = (const float*)d_in[0];
    const float* x        = (const float*)d_in[1];
    const int*   ei       = (const int*)d_in[2];
    const float* ea       = (const float*)d_in[3];
    const float* phi_w1   = (const float*)d_in[4];
    const float* phi_b1   = (const float*)d_in[5];
    const float* phi_w2   = (const float*)d_in[6];
    const float* phi_b2   = (const float*)d_in[7];
    const float* rho_w1   = (const float*)d_in[8];
    const float* rho_b1   = (const float*)d_in[9];
    const float* rho_w2   = (const float*)d_in[10];
    const float* rho_b2   = (const float*)d_in[11];
    const float* dr_w     = (const float*)d_in[12];
    const float* dr_b     = (const float*)d_in[13];
    const float* conv_eps = (const float*)d_in[14];
    const float* edge_w   = (const float*)d_in[15];
    const float* edge_b   = (const float*)d_in[16];
    const float* mlp_w1   = (const float*)d_in[17];
    const float* mlp_b1   = (const float*)d_in[18];
    const float* bn_g     = (const float*)d_in[19];
    const float* bn_b     = (const float*)d_in[20];
    const float* bn_m     = (const float*)d_in[21];
    const float* bn_v     = (const float*)d_in[22];
    const float* mlp_w2   = (const float*)d_in[23];
    const float* mlp_b2   = (const float*)d_in[24];
    const float* aggr_w   = (const float*)d_in[25];
    const float* aggr_b   = (const float*)d_in[26];

    float* out = (float*)d_out;

    // workspace layout
    float* h_buf   = (float*)d_ws;                       // N*H
    float* agg_buf = h_buf + (size_t)N_NODES * H;        // N*H
    int*   off     = (int*)(agg_buf + (size_t)N_NODES * H); // N+1
    int*   cursor  = off + (N_NODES + 1);                // N
    int*   csr_src = cursor + N_NODES;                   // E
    float* csr_a   = (float*)(csr_src + E_EDGES);        // E

    const int eblocks = (E_EDGES + 255) / 256;           // 3125

    // K1: node embeddings -> h  (independent of CSR build; FIFO stream ok)
    k_embed<<<N_NODES, 256, 0, stream>>>(
        ensemble, x, phi_w1, phi_b1, phi_w2, phi_b2,
        rho_w1, rho_b1, rho_w2, rho_b2, dr_w, dr_b, h_buf);

    // CSR build (once; edge_index is the same for all layers)
    hipMemsetAsync(off, 0, (N_NODES + 1) * sizeof(int), stream);
    k_count<<<eblocks, 256, 0, stream>>>(ei, off);
    k_scan<<<1, 1024, 0, stream>>>(off, cursor);
    k_fill<<<eblocks, 256, 0, stream>>>(ei, ea, cursor, csr_src, csr_a);

    // GINE layers
    const int gine_blocks = N_NODES / NPB;               // 6250
    for (int i = 0; i < L_LAYERS; ++i) {
        k_agg<<<N_NODES / 4, 256, 0, stream>>>(
            off, csr_src, csr_a, h_buf,
            edge_w + (size_t)i * H, edge_b + (size_t)i * H, agg_buf);
        k_gine<<<gine_blocks, 256, 0, stream>>>(
            agg_buf, h_buf, conv_eps + i,
            mlp_w1 + (size_t)i * H * H, mlp_b1 + (size_t)i * H,
            bn_g + (size_t)i * H, bn_b + (size_t)i * H,
            bn_m + (size_t)i * H, bn_v + (size_t)i * H,
            mlp_w2 + (size_t)i * H * H, mlp_b2 + (size_t)i * H,
            (i == 0) ? 1 : 0);
    }

    // K4: output head
    k_out<<<N_NODES / 2, 256, 0, stream>>>(h_buf, aggr_w, aggr_b, out);
}

// Round 3
// 1521.533 us; speedup vs baseline: 3.5196x; 1.1405x over previous
//
#include <hip/hip_runtime.h>
#include <math.h>

#define N_NODES 50000
#define M_ENS   20
#define C_IN    32
#define H       128
#define E_EDGES 800000
#define L_LAYERS 3
#define BN_EPS  1e-5f

// ---------------------------------------------------------------------------
// k_fold: precompute folded weights (once per launch, tiny):
//   Wf1 = phi_w2 @ rho_w1                  bf1 = 20*phi_b2 @ rho_w1 + rho_b1
//   Wf2 = rho_w2 @ dr_w[32:]               bf2 = rho_b2 @ dr_w[32:] + dr_b
// Valid because sum_m(relu_hid_m @ w2) == (sum_m relu_hid_m) @ w2 and the
// rho1-input / dr-input are linear images of hsum / t1.
// Grid = 128 blocks (one output column each), 256 threads.
// ---------------------------------------------------------------------------
__global__ __launch_bounds__(256) void k_fold(
    const float* __restrict__ w2,  const float* __restrict__ b2,
    const float* __restrict__ rw1, const float* __restrict__ rb1,
    const float* __restrict__ rw2, const float* __restrict__ rb2,
    const float* __restrict__ dr_w, const float* __restrict__ dr_b,
    float* __restrict__ Wf1, float* __restrict__ bf1,
    float* __restrict__ Wf2, float* __restrict__ bf2)
{
    const int j = blockIdx.x;      // output column
    const int t = threadIdx.x;

    __shared__ float s_c1[H];      // rho_w1[:, j]
    __shared__ float s_c2[H];      // dr_w[32+:, j]
    if (t < H) s_c1[t] = rw1[t * H + j];
    else       s_c2[t - H] = dr_w[(C_IN + (t - H)) * H + j];
    __syncthreads();

    if (t < H) {
        float acc = 0.f;
        for (int l = 0; l < H; ++l) acc = fmaf(w2[t * H + l], s_c1[l], acc);
        Wf1[t * H + j] = acc;
    } else {
        const int k = t - H;
        float acc = 0.f;
        for (int l = 0; l < H; ++l) acc = fmaf(rw2[k * H + l], s_c2[l], acc);
        Wf2[k * H + j] = acc;
    }
    if (t == 0) {
        float acc = rb1[j];
        for (int k = 0; k < H; ++k) acc = fmaf(20.f * b2[k], s_c1[k], acc);
        bf1[j] = acc;
    }
    if (t == 1) {
        float acc = dr_b[j];
        for (int k = 0; k < H; ++k) acc = fmaf(rb2[k], s_c2[k], acc);
        bf2[j] = acc;
    }
}

// ---------------------------------------------------------------------------
// k_embed: per-node chain with folded weights.
//   hsum = sum_m relu(ens_m @ w1 + b1)
//   t1   = relu(hsum @ Wf1 + bf1)
//   h    = t1 @ Wf2 + x @ dr_w[:32] + bf2
// 8 nodes / 256-thread block. Thread tile = 2 nodes x 2 columns for
// >=2:1 FMA:load density. w1 columns live in registers.
// ---------------------------------------------------------------------------
#define ENB 8
__global__ __launch_bounds__(256) void k_embed(
    const float* __restrict__ ensemble, const float* __restrict__ x,
    const float* __restrict__ phi_w1,   const float* __restrict__ phi_b1,
    const float* __restrict__ Wf1, const float* __restrict__ bf1,
    const float* __restrict__ Wf2, const float* __restrict__ bf2,
    const float* __restrict__ dr_w,
    float* __restrict__ h_out)
{
    const int n0 = blockIdx.x * ENB;
    const int t  = threadIdx.x;
    const int jp = t & 63;  const int j0 = jp * 2;
    const int np = t >> 6;  const int na = np * 2, nb = na + 1;

    __shared__ float s_ens[ENB * M_ENS * C_IN];  // 20 KB
    __shared__ float s_h[ENB][H];                // 4 KB
    __shared__ float s_t[ENB][H];                // 4 KB
    __shared__ float s_x[ENB][C_IN];             // 1 KB

    for (int i = t; i < ENB * M_ENS * C_IN; i += 256)
        s_ens[i] = ensemble[(size_t)n0 * (M_ENS * C_IN) + i];
    s_x[t >> 5][t & 31] = x[(size_t)n0 * C_IN + t];   // 256 == ENB*C_IN
    __syncthreads();

    // w1 columns j0, j0+1 -> registers
    float w1a[C_IN], w1b[C_IN];
    #pragma unroll
    for (int k = 0; k < C_IN; ++k) {
        w1a[k] = phi_w1[k * H + j0];
        w1b[k] = phi_w1[k * H + j0 + 1];
    }
    const float b1a = phi_b1[j0], b1b = phi_b1[j0 + 1];

    // ---- stage 1: hsum ----
    float hs00 = 0.f, hs01 = 0.f, hs10 = 0.f, hs11 = 0.f;
    for (int m = 0; m < M_ENS; ++m) {
        float a00 = b1a, a01 = b1b, a10 = b1a, a11 = b1b;
        const float* ea = &s_ens[(na * M_ENS + m) * C_IN];
        const float* eb = &s_ens[(nb * M_ENS + m) * C_IN];
        #pragma unroll
        for (int k = 0; k < C_IN; k += 2) {
            const float2 e0 = *(const float2*)&ea[k];
            const float2 e1 = *(const float2*)&eb[k];
            a00 = fmaf(e0.x, w1a[k], a00); a01 = fmaf(e0.x, w1b[k], a01);
            a10 = fmaf(e1.x, w1a[k], a10); a11 = fmaf(e1.x, w1b[k], a11);
            a00 = fmaf(e0.y, w1a[k+1], a00); a01 = fmaf(e0.y, w1b[k+1], a01);
            a10 = fmaf(e1.y, w1a[k+1], a10); a11 = fmaf(e1.y, w1b[k+1], a11);
        }
        hs00 += fmaxf(a00, 0.f); hs01 += fmaxf(a01, 0.f);
        hs10 += fmaxf(a10, 0.f); hs11 += fmaxf(a11, 0.f);
    }
    s_h[na][j0] = hs00; s_h[na][j0 + 1] = hs01;
    s_h[nb][j0] = hs10; s_h[nb][j0 + 1] = hs11;
    __syncthreads();

    // ---- stage 2: t1 = relu(hsum @ Wf1 + bf1) ----
    {
        const float2 bf = *(const float2*)&bf1[j0];
        float a00 = bf.x, a01 = bf.y, a10 = bf.x, a11 = bf.y;
        for (int k = 0; k < H; k += 2) {
            const float2 w0 = *(const float2*)&Wf1[k * H + j0];
            const float2 w1v = *(const float2*)&Wf1[(k + 1) * H + j0];
            const float2 h0 = *(const float2*)&s_h[na][k];
            const float2 h1 = *(const float2*)&s_h[nb][k];
            a00 = fmaf(h0.x, w0.x, a00); a01 = fmaf(h0.x, w0.y, a01);
            a10 = fmaf(h1.x, w0.x, a10); a11 = fmaf(h1.x, w0.y, a11);
            a00 = fmaf(h0.y, w1v.x, a00); a01 = fmaf(h0.y, w1v.y, a01);
            a10 = fmaf(h1.y, w1v.x, a10); a11 = fmaf(h1.y, w1v.y, a11);
        }
        s_t[na][j0] = fmaxf(a00, 0.f); s_t[na][j0 + 1] = fmaxf(a01, 0.f);
        s_t[nb][j0] = fmaxf(a10, 0.f); s_t[nb][j0 + 1] = fmaxf(a11, 0.f);
    }
    __syncthreads();

    // ---- stage 3: h = t1 @ Wf2 + x @ dr_w[:32] + bf2 ----
    {
        const float2 bf = *(const float2*)&bf2[j0];
        float a00 = bf.x, a01 = bf.y, a10 = bf.x, a11 = bf.y;
        for (int k = 0; k < H; k += 2) {
            const float2 w0 = *(const float2*)&Wf2[k * H + j0];
            const float2 w1v = *(const float2*)&Wf2[(k + 1) * H + j0];
            const float2 t0 = *(const float2*)&s_t[na][k];
            const float2 t1 = *(const float2*)&s_t[nb][k];
            a00 = fmaf(t0.x, w0.x, a00); a01 = fmaf(t0.x, w0.y, a01);
            a10 = fmaf(t1.x, w0.x, a10); a11 = fmaf(t1.x, w0.y, a11);
            a00 = fmaf(t0.y, w1v.x, a00); a01 = fmaf(t0.y, w1v.y, a01);
            a10 = fmaf(t1.y, w1v.x, a10); a11 = fmaf(t1.y, w1v.y, a11);
        }
        #pragma unroll
        for (int k = 0; k < C_IN; k += 2) {
            const float2 w0 = *(const float2*)&dr_w[k * H + j0];
            const float2 w1v = *(const float2*)&dr_w[(k + 1) * H + j0];
            const float2 x0 = *(const float2*)&s_x[na][k];
            const float2 x1 = *(const float2*)&s_x[nb][k];
            a00 = fmaf(x0.x, w0.x, a00); a01 = fmaf(x0.x, w0.y, a01);
            a10 = fmaf(x1.x, w0.x, a10); a11 = fmaf(x1.x, w0.y, a11);
            a00 = fmaf(x0.y, w1v.x, a00); a01 = fmaf(x0.y, w1v.y, a01);
            a10 = fmaf(x1.y, w1v.x, a10); a11 = fmaf(x1.y, w1v.y, a11);
        }
        float2 ra; ra.x = a00; ra.y = a01;
        float2 rb2v; rb2v.x = a10; rb2v.y = a11;
        *(float2*)&h_out[(size_t)(n0 + na) * H + j0] = ra;
        *(float2*)&h_out[(size_t)(n0 + nb) * H + j0] = rb2v;
    }
}

// ---------------------------------------------------------------------------
// CSR build (unchanged).
// ---------------------------------------------------------------------------
__global__ __launch_bounds__(256) void k_count(
    const int* __restrict__ ei, int* __restrict__ deg)
{
    const int e = blockIdx.x * 256 + threadIdx.x;
    if (e >= E_EDGES) return;
    atomicAdd(&deg[ei[E_EDGES + e]], 1);
}

__global__ __launch_bounds__(1024) void k_scan(
    int* __restrict__ off, int* __restrict__ cursor)
{
    const int t = threadIdx.x;
    const int CHUNK = (N_NODES + 1023) / 1024;
    const int lo = t * CHUNK;
    const int hi = min(lo + CHUNK, N_NODES);

    int mysum = 0;
    for (int i = lo; i < hi; ++i) mysum += off[i];

    __shared__ int s[1024];
    s[t] = mysum;
    __syncthreads();
    for (int d = 1; d < 1024; d <<= 1) {
        int v = (t >= d) ? s[t - d] : 0;
        __syncthreads();
        s[t] += v;
        __syncthreads();
    }
    int running = s[t] - mysum;

    for (int i = lo; i < hi; ++i) {
        const int d = off[i];
        off[i] = running;
        cursor[i] = running;
        running += d;
    }
    if (t == 0) off[N_NODES] = E_EDGES;
}

__global__ __launch_bounds__(256) void k_fill(
    const int* __restrict__ ei, const float* __restrict__ ea,
    int* __restrict__ cursor,
    int* __restrict__ csr_src, float* __restrict__ csr_a)
{
    const int e = blockIdx.x * 256 + threadIdx.x;
    if (e >= E_EDGES) return;
    const int dst = ei[E_EDGES + e];
    const int pos = atomicAdd(&cursor[dst], 1);
    csr_src[pos] = ei[e];
    csr_a[pos]   = ea[e];
}

// ---------------------------------------------------------------------------
// k_agg: CSR gather aggregation (unchanged).
// ---------------------------------------------------------------------------
__global__ __launch_bounds__(256) void k_agg(
    const int* __restrict__ off, const int* __restrict__ csr_src,
    const float* __restrict__ csr_a,
    const float* __restrict__ h, const float* __restrict__ ew,
    const float* __restrict__ eb, float* __restrict__ agg)
{
    const int wave = threadIdx.x >> 6;
    const int lane = threadIdx.x & 63;
    const int n = blockIdx.x * 4 + wave;
    const int c = lane * 2;

    const float2 wv = *(const float2*)&ew[c];
    const float2 bv = *(const float2*)&eb[c];

    float a0 = 0.f, a1 = 0.f;
    const int s = off[n], e = off[n + 1];
    for (int i = s; i < e; ++i) {
        const int   src = csr_src[i];
        const float a   = csr_a[i];
        const float2 hv = *(const float2*)&h[(size_t)src * H + c];
        a0 += fmaxf(fmaf(a, wv.x, hv.x) + bv.x, 0.f);
        a1 += fmaxf(fmaf(a, wv.y, hv.y) + bv.y, 0.f);
    }
    float2 r; r.x = a0; r.y = a1;
    *(float2*)&agg[(size_t)n * H + c] = r;
}

// ---------------------------------------------------------------------------
// k_gine: node update, 2-node x 2-col register tiling (BN folded per column).
//   z = (1+eps)*h + agg; t = relu(BN(z@w1+b1)); c = t@w2+b2
//   h = relu(c) (layer 0) or h + relu(c)
// 8 nodes / 256-thread block.
// ---------------------------------------------------------------------------
#define NPB 8
__global__ __launch_bounds__(256) void k_gine(
    const float* __restrict__ agg, float* __restrict__ h,
    const float* __restrict__ eps_p,
    const float* __restrict__ w1, const float* __restrict__ b1,
    const float* __restrict__ bn_g, const float* __restrict__ bn_b,
    const float* __restrict__ bn_m, const float* __restrict__ bn_v,
    const float* __restrict__ w2, const float* __restrict__ b2,
    const int first_layer)
{
    const int n0 = blockIdx.x * NPB;
    const int t  = threadIdx.x;
    const int jp = t & 63;  const int j0 = jp * 2;
    const int np = t >> 6;  const int na = np * 2, nb = na + 1;

    __shared__ float s_z[NPB][H];
    __shared__ float s_t[NPB][H];
    __shared__ float s_r[NPB][H];

    const float ep1 = 1.f + eps_p[0];

    for (int i = t; i < NPB * H; i += 256) {
        const int q = i >> 7, c = i & 127;
        const int n = n0 + q;
        const float hv = h[(size_t)n * H + c];
        const float av = agg[(size_t)n * H + c];
        s_r[q][c] = hv;
        s_z[q][c] = fmaf(ep1, hv, av);
    }
    __syncthreads();

    // matmul1 + BN + relu
    {
        // fold: y = (acc + b1 - m) * scale + b,  scale = g*rsqrt(v+eps)
        const float2 g = *(const float2*)&bn_g[j0];
        const float2 b = *(const float2*)&bn_b[j0];
        const float2 m = *(const float2*)&bn_m[j0];
        const float2 v = *(const float2*)&bn_v[j0];
        const float2 bb = *(const float2*)&b1[j0];
        const float scx = g.x * rsqrtf(v.x + BN_EPS);
        const float scy = g.y * rsqrtf(v.y + BN_EPS);
        const float shx = fmaf(bb.x - m.x, scx, b.x);
        const float shy = fmaf(bb.y - m.y, scy, b.y);

        float a00 = 0.f, a01 = 0.f, a10 = 0.f, a11 = 0.f;
        for (int k = 0; k < H; k += 2) {
            const float2 w0 = *(const float2*)&w1[k * H + j0];
            const float2 w1v = *(const float2*)&w1[(k + 1) * H + j0];
            const float2 z0 = *(const float2*)&s_z[na][k];
            const float2 z1 = *(const float2*)&s_z[nb][k];
            a00 = fmaf(z0.x, w0.x, a00); a01 = fmaf(z0.x, w0.y, a01);
            a10 = fmaf(z1.x, w0.x, a10); a11 = fmaf(z1.x, w0.y, a11);
            a00 = fmaf(z0.y, w1v.x, a00); a01 = fmaf(z0.y, w1v.y, a01);
            a10 = fmaf(z1.y, w1v.x, a10); a11 = fmaf(z1.y, w1v.y, a11);
        }
        s_t[na][j0]     = fmaxf(fmaf(a00, scx, shx), 0.f);
        s_t[na][j0 + 1] = fmaxf(fmaf(a01, scy, shy), 0.f);
        s_t[nb][j0]     = fmaxf(fmaf(a10, scx, shx), 0.f);
        s_t[nb][j0 + 1] = fmaxf(fmaf(a11, scy, shy), 0.f);
    }
    __syncthreads();

    // matmul2 + relu + residual
    {
        const float2 bb = *(const float2*)&b2[j0];
        float a00 = bb.x, a01 = bb.y, a10 = bb.x, a11 = bb.y;
        for (int k = 0; k < H; k += 2) {
            const float2 w0 = *(const float2*)&w2[k * H + j0];
            const float2 w1v = *(const float2*)&w2[(k + 1) * H + j0];
            const float2 t0 = *(const float2*)&s_t[na][k];
            const float2 t1 = *(const float2*)&s_t[nb][k];
            a00 = fmaf(t0.x, w0.x, a00); a01 = fmaf(t0.x, w0.y, a01);
            a10 = fmaf(t1.x, w0.x, a10); a11 = fmaf(t1.x, w0.y, a11);
            a00 = fmaf(t0.y, w1v.x, a00); a01 = fmaf(t0.y, w1v.y, a01);
            a10 = fmaf(t1.y, w1v.x, a10); a11 = fmaf(t1.y, w1v.y, a11);
        }
        float2 ra, rb;
        if (first_layer) {
            ra.x = fmaxf(a00, 0.f); ra.y = fmaxf(a01, 0.f);
            rb.x = fmaxf(a10, 0.f); rb.y = fmaxf(a11, 0.f);
        } else {
            ra.x = s_r[na][j0]     + fmaxf(a00, 0.f);
            ra.y = s_r[na][j0 + 1] + fmaxf(a01, 0.f);
            rb.x = s_r[nb][j0]     + fmaxf(a10, 0.f);
            rb.y = s_r[nb][j0 + 1] + fmaxf(a11, 0.f);
        }
        *(float2*)&h[(size_t)(n0 + na) * H + j0] = ra;
        *(float2*)&h[(size_t)(n0 + nb) * H + j0] = rb;
    }
}

// ---------------------------------------------------------------------------
// k_out: output head (unchanged).
// ---------------------------------------------------------------------------
__global__ __launch_bounds__(256) void k_out(
    const float* __restrict__ h, const float* __restrict__ aw,
    const float* __restrict__ ab, float* __restrict__ out)
{
    const int n = blockIdx.x * 2 + (threadIdx.x >> 7);
    const int j = threadIdx.x & 127;
    const int base = (threadIdx.x >> 7) << 7;

    __shared__ float r0[256];
    __shared__ float r1[256];

    const float hv = h[(size_t)n * H + j];
    r0[threadIdx.x] = hv * aw[j * 2 + 0];
    r1[threadIdx.x] = hv * aw[j * 2 + 1];
    __syncthreads();

    for (int s = 64; s > 0; s >>= 1) {
        if (j < s) {
            r0[base + j] += r0[base + j + s];
            r1[base + j] += r1[base + j + s];
        }
        __syncthreads();
    }
    if (j == 0) {
        const float mu = r0[base] + ab[0];
        const float o1 = r1[base] + ab[1];
        const float sp = (o1 > 0.f) ? (o1 + log1pf(expf(-o1)))
                                    : log1pf(expf(o1));
        out[(size_t)n * 2 + 0] = mu;
        out[(size_t)n * 2 + 1] = sp;
    }
}

// ---------------------------------------------------------------------------
extern "C" void kernel_launch(void* const* d_in, const int* in_sizes, int n_in,
                              void* d_out, int out_size, void* d_ws, size_t ws_size,
                              hipStream_t stream)
{
    const float* ensemble = (const float*)d_in[0];
    const float* x        = (const float*)d_in[1];
    const int*   ei       = (const int*)d_in[2];
    const float* ea       = (const float*)d_in[3];
    const float* phi_w1   = (const float*)d_in[4];
    const float* phi_b1   = (const float*)d_in[5];
    const float* phi_w2   = (const float*)d_in[6];
    const float* phi_b2   = (const float*)d_in[7];
    const float* rho_w1   = (const float*)d_in[8];
    const float* rho_b1   = (const float*)d_in[9];
    const float* rho_w2   = (const float*)d_in[10];
    const float* rho_b2   = (const float*)d_in[11];
    const float* dr_w     = (const float*)d_in[12];
    const float* dr_b     = (const float*)d_in[13];
    const float* conv_eps = (const float*)d_in[14];
    const float* edge_w   = (const float*)d_in[15];
    const float* edge_b   = (const float*)d_in[16];
    const float* mlp_w1   = (const float*)d_in[17];
    const float* mlp_b1   = (const float*)d_in[18];
    const float* bn_g     = (const float*)d_in[19];
    const float* bn_b     = (const float*)d_in[20];
    const float* bn_m     = (const float*)d_in[21];
    const float* bn_v     = (const float*)d_in[22];
    const float* mlp_w2   = (const float*)d_in[23];
    const float* mlp_b2   = (const float*)d_in[24];
    const float* aggr_w   = (const float*)d_in[25];
    const float* aggr_b   = (const float*)d_in[26];

    float* out = (float*)d_out;

    // workspace layout
    float* h_buf   = (float*)d_ws;                          // N*H
    float* agg_buf = h_buf + (size_t)N_NODES * H;           // N*H
    int*   off     = (int*)(agg_buf + (size_t)N_NODES * H); // N+1
    int*   cursor  = off + (N_NODES + 1);                   // N
    int*   csr_src = cursor + N_NODES;                      // E
    float* csr_a   = (float*)(csr_src + E_EDGES);           // E
    float* Wf1     = csr_a + E_EDGES;                       // H*H
    float* bf1     = Wf1 + H * H;                           // H
    float* Wf2     = bf1 + H;                               // H*H
    float* bf2     = Wf2 + H * H;                           // H

    const int eblocks = (E_EDGES + 255) / 256;

    // fold weights, then embed
    k_fold<<<H, 256, 0, stream>>>(phi_w2, phi_b2, rho_w1, rho_b1,
                                  rho_w2, rho_b2, dr_w, dr_b,
                                  Wf1, bf1, Wf2, bf2);
    k_embed<<<N_NODES / ENB, 256, 0, stream>>>(
        ensemble, x, phi_w1, phi_b1, Wf1, bf1, Wf2, bf2, dr_w, h_buf);

    // CSR build (once)
    hipMemsetAsync(off, 0, (N_NODES + 1) * sizeof(int), stream);
    k_count<<<eblocks, 256, 0, stream>>>(ei, off);
    k_scan<<<1, 1024, 0, stream>>>(off, cursor);
    k_fill<<<eblocks, 256, 0, stream>>>(ei, ea, cursor, csr_src, csr_a);

    // GINE layers
    for (int i = 0; i < L_LAYERS; ++i) {
        k_agg<<<N_NODES / 4, 256, 0, stream>>>(
            off, csr_src, csr_a, h_buf,
            edge_w + (size_t)i * H, edge_b + (size_t)i * H, agg_buf);
        k_gine<<<N_NODES / NPB, 256, 0, stream>>>(
            agg_buf, h_buf, conv_eps + i,
            mlp_w1 + (size_t)i * H * H, mlp_b1 + (size_t)i * H,
            bn_g + (size_t)i * H, bn_b + (size_t)i * H,
            bn_m + (size_t)i * H, bn_v + (size_t)i * H,
            mlp_w2 + (size_t)i * H * H, mlp_b2 + (size_t)i * H,
            (i == 0) ? 1 : 0);
    }

    k_out<<<N_NODES / 2, 256, 0, stream>>>(h_buf, aggr_w, aggr_b, out);
}

// Round 4
// 1406.939 us; speedup vs baseline: 3.8062x; 1.0814x over previous
//
#include <hip/hip_runtime.h>
#include <math.h>

#define N_NODES 50000
#define M_ENS   20
#define C_IN    32
#define H       128
#define E_EDGES 800000
#define L_LAYERS 3
#define BN_EPS  1e-5f

// ---------------------------------------------------------------------------
// k_fold: precompute folded weights (once per launch):
//   g=0: Wf1 = phi_w2 @ rho_w1,            bf1 = 20*phi_b2 @ rho_w1 + rho_b1
//   g=1: Wf2 = rho_w2 @ dr_w[32:],         bf2 = rho_b2 @ dr_w[32:] + dr_b
// 256 blocks: g = blk>>7 picks GEMM, j = blk&127 picks output column.
// 2 threads per output row, sequential float4 row streams, shfl-pair reduce.
// ---------------------------------------------------------------------------
__global__ __launch_bounds__(256) void k_fold(
    const float* __restrict__ w2,  const float* __restrict__ b2,
    const float* __restrict__ rw1, const float* __restrict__ rb1,
    const float* __restrict__ rw2, const float* __restrict__ rb2,
    const float* __restrict__ dr_w, const float* __restrict__ dr_b,
    float* __restrict__ Wf1, float* __restrict__ bf1,
    float* __restrict__ Wf2, float* __restrict__ bf2)
{
    const int g = blockIdx.x >> 7;
    const int j = blockIdx.x & 127;
    const int t = threadIdx.x;

    const float* A  = g ? rw2 : w2;
    const float* Bm = g ? (dr_w + C_IN * H) : rw1;

    __shared__ float s_col[H];
    if (t < H) s_col[t] = Bm[t * H + j];
    __syncthreads();

    const int r = t >> 1, q = t & 1;
    const float* arow = &A[r * H + q * 64];
    const float* cp = &s_col[q * 64];
    float acc = 0.f;
    #pragma unroll
    for (int u = 0; u < 64; u += 4) {
        const float4 av = *(const float4*)&arow[u];
        acc = fmaf(av.x, cp[u], acc);
        acc = fmaf(av.y, cp[u + 1], acc);
        acc = fmaf(av.z, cp[u + 2], acc);
        acc = fmaf(av.w, cp[u + 3], acc);
    }
    acc += __shfl_xor(acc, 1);
    if (q == 0) (g ? Wf2 : Wf1)[r * H + j] = acc;

    if (t == 0) {
        float bacc = g ? dr_b[j] : rb1[j];
        const float* bsrc = g ? rb2 : b2;
        const float scale = g ? 1.f : 20.f;
        for (int k = 0; k < H; ++k)
            bacc = fmaf(scale * bsrc[k], s_col[k], bacc);
        (g ? bf2 : bf1)[j] = bacc;
    }
}

// ---------------------------------------------------------------------------
// k_embed: per-node chain with folded weights (unchanged from R3).
// ---------------------------------------------------------------------------
#define ENB 8
__global__ __launch_bounds__(256) void k_embed(
    const float* __restrict__ ensemble, const float* __restrict__ x,
    const float* __restrict__ phi_w1,   const float* __restrict__ phi_b1,
    const float* __restrict__ Wf1, const float* __restrict__ bf1,
    const float* __restrict__ Wf2, const float* __restrict__ bf2,
    const float* __restrict__ dr_w,
    float* __restrict__ h_out)
{
    const int n0 = blockIdx.x * ENB;
    const int t  = threadIdx.x;
    const int jp = t & 63;  const int j0 = jp * 2;
    const int np = t >> 6;  const int na = np * 2, nb = na + 1;

    __shared__ float s_ens[ENB * M_ENS * C_IN];
    __shared__ float s_h[ENB][H];
    __shared__ float s_t[ENB][H];
    __shared__ float s_x[ENB][C_IN];

    for (int i = t; i < ENB * M_ENS * C_IN; i += 256)
        s_ens[i] = ensemble[(size_t)n0 * (M_ENS * C_IN) + i];
    s_x[t >> 5][t & 31] = x[(size_t)n0 * C_IN + t];
    __syncthreads();

    float w1a[C_IN], w1b[C_IN];
    #pragma unroll
    for (int k = 0; k < C_IN; ++k) {
        w1a[k] = phi_w1[k * H + j0];
        w1b[k] = phi_w1[k * H + j0 + 1];
    }
    const float b1a = phi_b1[j0], b1b = phi_b1[j0 + 1];

    float hs00 = 0.f, hs01 = 0.f, hs10 = 0.f, hs11 = 0.f;
    for (int m = 0; m < M_ENS; ++m) {
        float a00 = b1a, a01 = b1b, a10 = b1a, a11 = b1b;
        const float* ea = &s_ens[(na * M_ENS + m) * C_IN];
        const float* eb = &s_ens[(nb * M_ENS + m) * C_IN];
        #pragma unroll
        for (int k = 0; k < C_IN; k += 2) {
            const float2 e0 = *(const float2*)&ea[k];
            const float2 e1 = *(const float2*)&eb[k];
            a00 = fmaf(e0.x, w1a[k], a00); a01 = fmaf(e0.x, w1b[k], a01);
            a10 = fmaf(e1.x, w1a[k], a10); a11 = fmaf(e1.x, w1b[k], a11);
            a00 = fmaf(e0.y, w1a[k+1], a00); a01 = fmaf(e0.y, w1b[k+1], a01);
            a10 = fmaf(e1.y, w1a[k+1], a10); a11 = fmaf(e1.y, w1b[k+1], a11);
        }
        hs00 += fmaxf(a00, 0.f); hs01 += fmaxf(a01, 0.f);
        hs10 += fmaxf(a10, 0.f); hs11 += fmaxf(a11, 0.f);
    }
    s_h[na][j0] = hs00; s_h[na][j0 + 1] = hs01;
    s_h[nb][j0] = hs10; s_h[nb][j0 + 1] = hs11;
    __syncthreads();

    {
        const float2 bf = *(const float2*)&bf1[j0];
        float a00 = bf.x, a01 = bf.y, a10 = bf.x, a11 = bf.y;
        for (int k = 0; k < H; k += 2) {
            const float2 w0 = *(const float2*)&Wf1[k * H + j0];
            const float2 w1v = *(const float2*)&Wf1[(k + 1) * H + j0];
            const float2 h0 = *(const float2*)&s_h[na][k];
            const float2 h1 = *(const float2*)&s_h[nb][k];
            a00 = fmaf(h0.x, w0.x, a00); a01 = fmaf(h0.x, w0.y, a01);
            a10 = fmaf(h1.x, w0.x, a10); a11 = fmaf(h1.x, w0.y, a11);
            a00 = fmaf(h0.y, w1v.x, a00); a01 = fmaf(h0.y, w1v.y, a01);
            a10 = fmaf(h1.y, w1v.x, a10); a11 = fmaf(h1.y, w1v.y, a11);
        }
        s_t[na][j0] = fmaxf(a00, 0.f); s_t[na][j0 + 1] = fmaxf(a01, 0.f);
        s_t[nb][j0] = fmaxf(a10, 0.f); s_t[nb][j0 + 1] = fmaxf(a11, 0.f);
    }
    __syncthreads();

    {
        const float2 bf = *(const float2*)&bf2[j0];
        float a00 = bf.x, a01 = bf.y, a10 = bf.x, a11 = bf.y;
        for (int k = 0; k < H; k += 2) {
            const float2 w0 = *(const float2*)&Wf2[k * H + j0];
            const float2 w1v = *(const float2*)&Wf2[(k + 1) * H + j0];
            const float2 t0 = *(const float2*)&s_t[na][k];
            const float2 t1 = *(const float2*)&s_t[nb][k];
            a00 = fmaf(t0.x, w0.x, a00); a01 = fmaf(t0.x, w0.y, a01);
            a10 = fmaf(t1.x, w0.x, a10); a11 = fmaf(t1.x, w0.y, a11);
            a00 = fmaf(t0.y, w1v.x, a00); a01 = fmaf(t0.y, w1v.y, a01);
            a10 = fmaf(t1.y, w1v.x, a10); a11 = fmaf(t1.y, w1v.y, a11);
        }
        #pragma unroll
        for (int k = 0; k < C_IN; k += 2) {
            const float2 w0 = *(const float2*)&dr_w[k * H + j0];
            const float2 w1v = *(const float2*)&dr_w[(k + 1) * H + j0];
            const float2 x0 = *(const float2*)&s_x[na][k];
            const float2 x1 = *(const float2*)&s_x[nb][k];
            a00 = fmaf(x0.x, w0.x, a00); a01 = fmaf(x0.x, w0.y, a01);
            a10 = fmaf(x1.x, w0.x, a10); a11 = fmaf(x1.x, w0.y, a11);
            a00 = fmaf(x0.y, w1v.x, a00); a01 = fmaf(x0.y, w1v.y, a01);
            a10 = fmaf(x1.y, w1v.x, a10); a11 = fmaf(x1.y, w1v.y, a11);
        }
        float2 ra; ra.x = a00; ra.y = a01;
        float2 rb2v; rb2v.x = a10; rb2v.y = a11;
        *(float2*)&h_out[(size_t)(n0 + na) * H + j0] = ra;
        *(float2*)&h_out[(size_t)(n0 + nb) * H + j0] = rb2v;
    }
}

// ---------------------------------------------------------------------------
// CSR build. csr entries packed as int2{src, float_bits(edge_attr)}.
// ---------------------------------------------------------------------------
__global__ __launch_bounds__(256) void k_count(
    const int* __restrict__ ei, int* __restrict__ deg)
{
    const int e = blockIdx.x * 256 + threadIdx.x;
    if (e >= E_EDGES) return;
    atomicAdd(&deg[ei[E_EDGES + e]], 1);
}

__global__ __launch_bounds__(1024) void k_scan(
    int* __restrict__ off, int* __restrict__ cursor)
{
    const int t = threadIdx.x;
    const int CHUNK = (N_NODES + 1023) / 1024;
    const int lo = t * CHUNK;
    const int hi = min(lo + CHUNK, N_NODES);

    int mysum = 0;
    for (int i = lo; i < hi; ++i) mysum += off[i];

    __shared__ int s[1024];
    s[t] = mysum;
    __syncthreads();
    for (int d = 1; d < 1024; d <<= 1) {
        int v = (t >= d) ? s[t - d] : 0;
        __syncthreads();
        s[t] += v;
        __syncthreads();
    }
    int running = s[t] - mysum;

    for (int i = lo; i < hi; ++i) {
        const int d = off[i];
        off[i] = running;
        cursor[i] = running;
        running += d;
    }
    if (t == 0) off[N_NODES] = E_EDGES;
}

__global__ __launch_bounds__(256) void k_fill(
    const int* __restrict__ ei, const float* __restrict__ ea,
    int* __restrict__ cursor, int2* __restrict__ csr)
{
    const int e = blockIdx.x * 256 + threadIdx.x;
    if (e >= E_EDGES) return;
    const int dst = ei[E_EDGES + e];
    const int pos = atomicAdd(&cursor[dst], 1);
    csr[pos] = make_int2(ei[e], __float_as_int(ea[e]));
}

// ---------------------------------------------------------------------------
// k_agg: CSR gather aggregation, MLP-optimized.
// One wave per node. Each 32-lane half owns the full 128-ch row (float4/lane)
// and processes alternating edges; unroll x2 -> 4 independent gathers in
// flight per wave. Cross-half combine via shfl_xor(32).
// ---------------------------------------------------------------------------
__global__ __launch_bounds__(256) void k_agg(
    const int* __restrict__ off, const int2* __restrict__ csr,
    const float* __restrict__ h, const float* __restrict__ ew,
    const float* __restrict__ eb, float* __restrict__ agg)
{
    const int wave = threadIdx.x >> 6;
    const int lane = threadIdx.x & 63;
    const int half = lane >> 5;
    const int c = (lane & 31) * 4;
    const int n = blockIdx.x * 4 + wave;

    const float4 wv = *(const float4*)&ew[c];
    const float4 bv = *(const float4*)&eb[c];

    const int s = off[n], e = off[n + 1];

    float ax0 = 0.f, ay0 = 0.f, az0 = 0.f, aw0 = 0.f;
    float ax1 = 0.f, ay1 = 0.f, az1 = 0.f, aw1 = 0.f;
    int i = s + half;
    for (; i + 2 < e; i += 4) {
        const int2 p0 = csr[i];
        const int2 p1 = csr[i + 2];
        const float4 h0 = *(const float4*)&h[(size_t)p0.x * H + c];
        const float4 h1 = *(const float4*)&h[(size_t)p1.x * H + c];
        const float a0 = __int_as_float(p0.y);
        const float a1 = __int_as_float(p1.y);
        ax0 += fmaxf(fmaf(a0, wv.x, h0.x) + bv.x, 0.f);
        ay0 += fmaxf(fmaf(a0, wv.y, h0.y) + bv.y, 0.f);
        az0 += fmaxf(fmaf(a0, wv.z, h0.z) + bv.z, 0.f);
        aw0 += fmaxf(fmaf(a0, wv.w, h0.w) + bv.w, 0.f);
        ax1 += fmaxf(fmaf(a1, wv.x, h1.x) + bv.x, 0.f);
        ay1 += fmaxf(fmaf(a1, wv.y, h1.y) + bv.y, 0.f);
        az1 += fmaxf(fmaf(a1, wv.z, h1.z) + bv.z, 0.f);
        aw1 += fmaxf(fmaf(a1, wv.w, h1.w) + bv.w, 0.f);
    }
    if (i < e) {
        const int2 p0 = csr[i];
        const float4 h0 = *(const float4*)&h[(size_t)p0.x * H + c];
        const float a0 = __int_as_float(p0.y);
        ax0 += fmaxf(fmaf(a0, wv.x, h0.x) + bv.x, 0.f);
        ay0 += fmaxf(fmaf(a0, wv.y, h0.y) + bv.y, 0.f);
        az0 += fmaxf(fmaf(a0, wv.z, h0.z) + bv.z, 0.f);
        aw0 += fmaxf(fmaf(a0, wv.w, h0.w) + bv.w, 0.f);
    }
    ax0 += ax1; ay0 += ay1; az0 += az1; aw0 += aw1;
    ax0 += __shfl_xor(ax0, 32);
    ay0 += __shfl_xor(ay0, 32);
    az0 += __shfl_xor(az0, 32);
    aw0 += __shfl_xor(aw0, 32);
    if (half == 0) {
        float4 r; r.x = ax0; r.y = ay0; r.z = az0; r.w = aw0;
        *(float4*)&agg[(size_t)n * H + c] = r;
    }
}

// ---------------------------------------------------------------------------
// k_gine: node update, 2-node x 2-col register tiling (unchanged from R3).
// ---------------------------------------------------------------------------
#define NPB 8
__global__ __launch_bounds__(256) void k_gine(
    const float* __restrict__ agg, float* __restrict__ h,
    const float* __restrict__ eps_p,
    const float* __restrict__ w1, const float* __restrict__ b1,
    const float* __restrict__ bn_g, const float* __restrict__ bn_b,
    const float* __restrict__ bn_m, const float* __restrict__ bn_v,
    const float* __restrict__ w2, const float* __restrict__ b2,
    const int first_layer)
{
    const int n0 = blockIdx.x * NPB;
    const int t  = threadIdx.x;
    const int jp = t & 63;  const int j0 = jp * 2;
    const int np = t >> 6;  const int na = np * 2, nb = na + 1;

    __shared__ float s_z[NPB][H];
    __shared__ float s_t[NPB][H];
    __shared__ float s_r[NPB][H];

    const float ep1 = 1.f + eps_p[0];

    for (int i = t; i < NPB * H; i += 256) {
        const int q = i >> 7, c = i & 127;
        const int n = n0 + q;
        const float hv = h[(size_t)n * H + c];
        const float av = agg[(size_t)n * H + c];
        s_r[q][c] = hv;
        s_z[q][c] = fmaf(ep1, hv, av);
    }
    __syncthreads();

    {
        const float2 g = *(const float2*)&bn_g[j0];
        const float2 b = *(const float2*)&bn_b[j0];
        const float2 m = *(const float2*)&bn_m[j0];
        const float2 v = *(const float2*)&bn_v[j0];
        const float2 bb = *(const float2*)&b1[j0];
        const float scx = g.x * rsqrtf(v.x + BN_EPS);
        const float scy = g.y * rsqrtf(v.y + BN_EPS);
        const float shx = fmaf(bb.x - m.x, scx, b.x);
        const float shy = fmaf(bb.y - m.y, scy, b.y);

        float a00 = 0.f, a01 = 0.f, a10 = 0.f, a11 = 0.f;
        for (int k = 0; k < H; k += 2) {
            const float2 w0 = *(const float2*)&w1[k * H + j0];
            const float2 w1v = *(const float2*)&w1[(k + 1) * H + j0];
            const float2 z0 = *(const float2*)&s_z[na][k];
            const float2 z1 = *(const float2*)&s_z[nb][k];
            a00 = fmaf(z0.x, w0.x, a00); a01 = fmaf(z0.x, w0.y, a01);
            a10 = fmaf(z1.x, w0.x, a10); a11 = fmaf(z1.x, w0.y, a11);
            a00 = fmaf(z0.y, w1v.x, a00); a01 = fmaf(z0.y, w1v.y, a01);
            a10 = fmaf(z1.y, w1v.x, a10); a11 = fmaf(z1.y, w1v.y, a11);
        }
        s_t[na][j0]     = fmaxf(fmaf(a00, scx, shx), 0.f);
        s_t[na][j0 + 1] = fmaxf(fmaf(a01, scy, shy), 0.f);
        s_t[nb][j0]     = fmaxf(fmaf(a10, scx, shx), 0.f);
        s_t[nb][j0 + 1] = fmaxf(fmaf(a11, scy, shy), 0.f);
    }
    __syncthreads();

    {
        const float2 bb = *(const float2*)&b2[j0];
        float a00 = bb.x, a01 = bb.y, a10 = bb.x, a11 = bb.y;
        for (int k = 0; k < H; k += 2) {
            const float2 w0 = *(const float2*)&w2[k * H + j0];
            const float2 w1v = *(const float2*)&w2[(k + 1) * H + j0];
            const float2 t0 = *(const float2*)&s_t[na][k];
            const float2 t1 = *(const float2*)&s_t[nb][k];
            a00 = fmaf(t0.x, w0.x, a00); a01 = fmaf(t0.x, w0.y, a01);
            a10 = fmaf(t1.x, w0.x, a10); a11 = fmaf(t1.x, w0.y, a11);
            a00 = fmaf(t0.y, w1v.x, a00); a01 = fmaf(t0.y, w1v.y, a01);
            a10 = fmaf(t1.y, w1v.x, a10); a11 = fmaf(t1.y, w1v.y, a11);
        }
        float2 ra, rb;
        if (first_layer) {
            ra.x = fmaxf(a00, 0.f); ra.y = fmaxf(a01, 0.f);
            rb.x = fmaxf(a10, 0.f); rb.y = fmaxf(a11, 0.f);
        } else {
            ra.x = s_r[na][j0]     + fmaxf(a00, 0.f);
            ra.y = s_r[na][j0 + 1] + fmaxf(a01, 0.f);
            rb.x = s_r[nb][j0]     + fmaxf(a10, 0.f);
            rb.y = s_r[nb][j0 + 1] + fmaxf(a11, 0.f);
        }
        *(float2*)&h[(size_t)(n0 + na) * H + j0] = ra;
        *(float2*)&h[(size_t)(n0 + nb) * H + j0] = rb;
    }
}

// ---------------------------------------------------------------------------
// k_out: output head (unchanged).
// ---------------------------------------------------------------------------
__global__ __launch_bounds__(256) void k_out(
    const float* __restrict__ h, const float* __restrict__ aw,
    const float* __restrict__ ab, float* __restrict__ out)
{
    const int n = blockIdx.x * 2 + (threadIdx.x >> 7);
    const int j = threadIdx.x & 127;
    const int base = (threadIdx.x >> 7) << 7;

    __shared__ float r0[256];
    __shared__ float r1[256];

    const float hv = h[(size_t)n * H + j];
    r0[threadIdx.x] = hv * aw[j * 2 + 0];
    r1[threadIdx.x] = hv * aw[j * 2 + 1];
    __syncthreads();

    for (int s = 64; s > 0; s >>= 1) {
        if (j < s) {
            r0[base + j] += r0[base + j + s];
            r1[base + j] += r1[base + j + s];
        }
        __syncthreads();
    }
    if (j == 0) {
        const float mu = r0[base] + ab[0];
        const float o1 = r1[base] + ab[1];
        const float sp = (o1 > 0.f) ? (o1 + log1pf(expf(-o1)))
                                    : log1pf(expf(o1));
        out[(size_t)n * 2 + 0] = mu;
        out[(size_t)n * 2 + 1] = sp;
    }
}

// ---------------------------------------------------------------------------
extern "C" void kernel_launch(void* const* d_in, const int* in_sizes, int n_in,
                              void* d_out, int out_size, void* d_ws, size_t ws_size,
                              hipStream_t stream)
{
    const float* ensemble = (const float*)d_in[0];
    const float* x        = (const float*)d_in[1];
    const int*   ei       = (const int*)d_in[2];
    const float* ea       = (const float*)d_in[3];
    const float* phi_w1   = (const float*)d_in[4];
    const float* phi_b1   = (const float*)d_in[5];
    const float* phi_w2   = (const float*)d_in[6];
    const float* phi_b2   = (const float*)d_in[7];
    const float* rho_w1   = (const float*)d_in[8];
    const float* rho_b1   = (const float*)d_in[9];
    const float* rho_w2   = (const float*)d_in[10];
    const float* rho_b2   = (const float*)d_in[11];
    const float* dr_w     = (const float*)d_in[12];
    const float* dr_b     = (const float*)d_in[13];
    const float* conv_eps = (const float*)d_in[14];
    const float* edge_w   = (const float*)d_in[15];
    const float* edge_b   = (const float*)d_in[16];
    const float* mlp_w1   = (const float*)d_in[17];
    const float* mlp_b1   = (const float*)d_in[18];
    const float* bn_g     = (const float*)d_in[19];
    const float* bn_b     = (const float*)d_in[20];
    const float* bn_m     = (const float*)d_in[21];
    const float* bn_v     = (const float*)d_in[22];
    const float* mlp_w2   = (const float*)d_in[23];
    const float* mlp_b2   = (const float*)d_in[24];
    const float* aggr_w   = (const float*)d_in[25];
    const float* aggr_b   = (const float*)d_in[26];

    float* out = (float*)d_out;

    // workspace layout (int2 csr needs 8B alignment -> pad off to even count)
    float* h_buf   = (float*)d_ws;                          // N*H
    float* agg_buf = h_buf + (size_t)N_NODES * H;           // N*H
    float* Wf1     = agg_buf + (size_t)N_NODES * H;         // H*H
    float* bf1     = Wf1 + H * H;                           // H
    float* Wf2     = bf1 + H;                               // H*H
    float* bf2     = Wf2 + H * H;                           // H
    int*   off     = (int*)(bf2 + H);                       // N+2 (padded)
    int*   cursor  = off + (N_NODES + 2);                   // N
    int2*  csr     = (int2*)(cursor + N_NODES);             // E (8B aligned)

    const int eblocks = (E_EDGES + 255) / 256;

    // fold weights, then embed
    k_fold<<<256, 256, 0, stream>>>(phi_w2, phi_b2, rho_w1, rho_b1,
                                    rho_w2, rho_b2, dr_w, dr_b,
                                    Wf1, bf1, Wf2, bf2);
    k_embed<<<N_NODES / ENB, 256, 0, stream>>>(
        ensemble, x, phi_w1, phi_b1, Wf1, bf1, Wf2, bf2, dr_w, h_buf);

    // CSR build (once)
    hipMemsetAsync(off, 0, (N_NODES + 1) * sizeof(int), stream);
    k_count<<<eblocks, 256, 0, stream>>>(ei, off);
    k_scan<<<1, 1024, 0, stream>>>(off, cursor);
    k_fill<<<eblocks, 256, 0, stream>>>(ei, ea, cursor, csr);

    // GINE layers
    for (int i = 0; i < L_LAYERS; ++i) {
        k_agg<<<N_NODES / 4, 256, 0, stream>>>(
            off, csr, h_buf,
            edge_w + (size_t)i * H, edge_b + (size_t)i * H, agg_buf);
        k_gine<<<N_NODES / NPB, 256, 0, stream>>>(
            agg_buf, h_buf, conv_eps + i,
            mlp_w1 + (size_t)i * H * H, mlp_b1 + (size_t)i * H,
            bn_g + (size_t)i * H, bn_b + (size_t)i * H,
            bn_m + (size_t)i * H, bn_v + (size_t)i * H,
            mlp_w2 + (size_t)i * H * H, mlp_b2 + (size_t)i * H,
            (i == 0) ? 1 : 0);
    }

    k_out<<<N_NODES / 2, 256, 0, stream>>>(h_buf, aggr_w, aggr_b, out);
}